// Round 1
// baseline (530.751 us; speedup 1.0000x reference)
//
#include <hip/hip_runtime.h>
#include <hip/hip_bf16.h>

typedef unsigned short u16;
typedef unsigned int u32;

#define NN 20000      // nodes
#define NE 320000     // edges
#define NG 128        // graphs
#define HD 128        // hidden
#define NH 4          // heads
#define BN_EPS 1e-5f

__device__ __forceinline__ float bf2f(u16 v){ return __uint_as_float(((u32)v)<<16); }
__device__ __forceinline__ u16 f2bf(float f){
    u32 u = __float_as_uint(f);
    return (u16)((u + 0x7fffu + ((u>>16)&1u)) >> 16);   // RNE
}

// ---- CSR build -------------------------------------------------------------
__global__ void k_hist(const int* __restrict__ dst, int* __restrict__ counts){
    int e = blockIdx.x*256 + threadIdx.x;
    if(e < NE) atomicAdd(&counts[dst[e]], 1);
}

__global__ void k_scan(const int* __restrict__ counts, int* __restrict__ rowptr,
                       int* __restrict__ cursor){
    __shared__ int wsum[16];
    int tx = threadIdx.x, lane = tx & 63, wid = tx >> 6;
    int running = 0;
    for(int t = 0; t < (NN + 1023)/1024; ++t){
        int i = t*1024 + tx;
        int v = (i < NN) ? counts[i] : 0;
        int s = v;
        #pragma unroll
        for(int d = 1; d < 64; d <<= 1){ int o = __shfl_up(s, d); if(lane >= d) s += o; }
        if(lane == 63) wsum[wid] = s;
        __syncthreads();
        int woff = 0, total = 0;
        for(int w_ = 0; w_ < 16; ++w_){ int sw = wsum[w_]; total += sw; if(w_ < wid) woff += sw; }
        int ex = running + woff + s - v;   // exclusive prefix
        if(i < NN){ rowptr[i] = ex; cursor[i] = ex; }
        running += total;
        __syncthreads();
    }
    if(tx == 0) rowptr[NN] = running;
}

__global__ void k_scatter(const int* __restrict__ src, const int* __restrict__ dst,
                          int* __restrict__ cursor, int* __restrict__ srcs,
                          int* __restrict__ dsts){
    int e = blockIdx.x*256 + threadIdx.x;
    if(e >= NE) return;
    int d = dst[e];
    int p = atomicAdd(&cursor[d], 1);
    srcs[p] = src[e];
    dsts[p] = d;
}

// ---- z = x @ W per head (vector-ALU GEMM, 16-node tiles) -------------------
template<int K, bool BF16IN>
__global__ void k_gemm(const float* __restrict__ xf, const u16* __restrict__ xb,
                       const float* __restrict__ W, u16* __restrict__ z){
    __shared__ float xs[16][K];
    int h  = blockIdx.y;
    int n0 = blockIdx.x * 16;
    int tx = threadIdx.x;                     // 128 threads = out channel
    for(int idx = tx; idx < 16*K; idx += 128){
        int i = idx / K, k = idx - i*K;
        int n = n0 + i;
        xs[i][k] = BF16IN ? bf2f(xb[n*K + k]) : xf[n*K + k];
    }
    __syncthreads();
    float acc[16];
    #pragma unroll
    for(int i = 0; i < 16; ++i) acc[i] = 0.f;
    const float* Wh = W + h*(K*HD) + tx;
    for(int k = 0; k < K; ++k){
        float w = Wh[k*HD];
        #pragma unroll
        for(int i = 0; i < 16; ++i) acc[i] += xs[i][k]*w;
    }
    #pragma unroll
    for(int i = 0; i < 16; ++i)
        z[((n0+i)*NH + h)*HD + tx] = f2bf(acc[i]);
}

// ---- per-node attention dot products es = z.a_src, ed = z.a_dst ------------
__global__ void k_dots(const u16* __restrict__ z, const float* __restrict__ attj,
                       float* __restrict__ es, float* __restrict__ ed){
    int tx = threadIdx.x, lane = tx & 63, w = tx >> 6;
    int n = blockIdx.x*4 + w;
    if(n >= NN) return;
    int ch = lane*2;
    for(int h = 0; h < NH; ++h){
        u32 zz = *(const u32*)(z + (size_t)(n*NH + h)*HD + ch);
        float z0 = bf2f((u16)(zz & 0xffffu));
        float z1 = bf2f((u16)(zz >> 16));
        const float* a = attj + h*2*HD;
        float ps = z0*a[ch]    + z1*a[ch+1];
        float pd = z0*a[HD+ch] + z1*a[HD+ch+1];
        #pragma unroll
        for(int d = 32; d > 0; d >>= 1){ ps += __shfl_xor(ps, d); pd += __shfl_xor(pd, d); }
        if(lane == 0){ es[n*NH + h] = ps; ed[n*NH + h] = pd; }
    }
}

// ---- edge logits (sorted order), leaky_relu slope 0.01 ---------------------
__global__ void k_elogits(const int* __restrict__ srcs, const int* __restrict__ dsts,
                          const float* __restrict__ es, const float* __restrict__ ed,
                          float* __restrict__ e4s){
    int p = blockIdx.x*256 + threadIdx.x;
    if(p >= NE) return;
    int s = srcs[p], d = dsts[p];
    float4 a = *(const float4*)(es + s*4);
    float4 b = *(const float4*)(ed + d*4);
    float4 e;
    e.x = a.x + b.x; e.y = a.y + b.y; e.z = a.z + b.z; e.w = a.w + b.w;
    e.x = e.x >= 0.f ? e.x : 0.01f*e.x;
    e.y = e.y >= 0.f ? e.y : 0.01f*e.y;
    e.z = e.z >= 0.f ? e.z : 0.01f*e.z;
    e.w = e.w >= 0.f ? e.w : 0.01f*e.w;
    *(float4*)(e4s + p*4) = e;
}

// ---- segment softmax + weighted aggregation + relu -------------------------
// block = node, wave = head, 2 channels/lane
__global__ void k_aggregate(const int* __restrict__ rowptr, const int* __restrict__ srcs,
                            const float* __restrict__ e4s, const u16* __restrict__ z,
                            u16* __restrict__ r){
    int n = blockIdx.x;
    int tx = threadIdx.x, lane = tx & 63, h = tx >> 6;
    int p0 = rowptr[n], p1 = rowptr[n+1];
    int ch = lane*2;
    float acc0 = 0.f, acc1 = 0.f;
    if(p1 > p0){
        float m = -1e30f;
        for(int p = p0 + lane; p < p1; p += 64) m = fmaxf(m, e4s[p*4 + h]);
        #pragma unroll
        for(int d = 32; d > 0; d >>= 1) m = fmaxf(m, __shfl_xor(m, d));
        float s = 0.f;
        for(int p = p0 + lane; p < p1; p += 64) s += __expf(e4s[p*4 + h] - m);
        #pragma unroll
        for(int d = 32; d > 0; d >>= 1) s += __shfl_xor(s, d);
        float inv = 1.f/s;
        for(int p = p0; p < p1; ++p){
            float a = __expf(e4s[p*4 + h] - m) * inv;
            int sn = srcs[p];
            u32 zz = *(const u32*)(z + (size_t)(sn*NH + h)*HD + ch);
            acc0 += a * bf2f((u16)(zz & 0xffffu));
            acc1 += a * bf2f((u16)(zz >> 16));
        }
    }
    acc0 = fmaxf(acc0, 0.f);
    acc1 = fmaxf(acc1, 0.f);
    u32 out = (u32)f2bf(acc0) | ((u32)f2bf(acc1) << 16);
    *(u32*)(r + (size_t)(n*NH + h)*HD + ch) = out;
}

// ---- BatchNorm stats (sum, sumsq per channel) ------------------------------
__global__ void k_bnreduce(const u16* __restrict__ r, float* __restrict__ bnsum,
                           float* __restrict__ bnsqs){
    int c = blockIdx.x*256 + threadIdx.x;   // 0..511
    int nbeg = blockIdx.y * 160;            // 125 chunks * 160 = 20000
    float s = 0.f, s2 = 0.f;
    for(int i = 0; i < 160; ++i){
        float v = bf2f(r[(size_t)(nbeg+i)*512 + c]);
        s += v; s2 += v*v;
    }
    atomicAdd(&bnsum[c], s);
    atomicAdd(&bnsqs[c], s2);
}

__global__ void k_bnfin(const float* __restrict__ bnsum, const float* __restrict__ bnsqs,
                        const float* __restrict__ gamma, const float* __restrict__ beta,
                        float* __restrict__ inv, float* __restrict__ shift){
    int c = blockIdx.x*256 + threadIdx.x;
    if(c >= 512) return;
    float mean = bnsum[c] * (1.f/NN);
    float var  = bnsqs[c] * (1.f/NN) - mean*mean;
    float iv = gamma[c] * rsqrtf(var + BN_EPS);
    inv[c] = iv;
    shift[c] = beta[c] - mean*iv;
}

// ---- BN apply + head softmax mix -> x[N][128] ------------------------------
// out_b omitted: softmax(v + const) == softmax(v)
__global__ void k_headmix(const u16* __restrict__ r, const float* __restrict__ inv,
                          const float* __restrict__ shift, const float* __restrict__ ow,
                          u16* __restrict__ x){
    int tx = threadIdx.x, lane = tx & 63, w = tx >> 6;
    int n = blockIdx.x*4 + w;
    if(n >= NN) return;
    int ch = lane*2;
    float rn[NH][2];
    float sc[NH];
    #pragma unroll
    for(int h = 0; h < NH; ++h){
        int c = h*HD + ch;
        u32 zz = *(const u32*)(r + (size_t)n*512 + c);
        float v0 = bf2f((u16)(zz & 0xffffu))*inv[c]   + shift[c];
        float v1 = bf2f((u16)(zz >> 16))   *inv[c+1] + shift[c+1];
        rn[h][0] = v0; rn[h][1] = v1;
        float p = v0*ow[ch] + v1*ow[ch+1];
        #pragma unroll
        for(int d = 32; d > 0; d >>= 1) p += __shfl_xor(p, d);
        sc[h] = p;
    }
    float m = fmaxf(fmaxf(sc[0], sc[1]), fmaxf(sc[2], sc[3]));
    float e0 = __expf(sc[0]-m), e1 = __expf(sc[1]-m), e2 = __expf(sc[2]-m), e3 = __expf(sc[3]-m);
    float is = 1.f/(e0+e1+e2+e3);
    float x0 = (e0*rn[0][0] + e1*rn[1][0] + e2*rn[2][0] + e3*rn[3][0])*is;
    float x1 = (e0*rn[0][1] + e1*rn[1][1] + e2*rn[2][1] + e3*rn[3][1])*is;
    *(u32*)(x + (size_t)n*HD + ch) = (u32)f2bf(x0) | ((u32)f2bf(x1) << 16);
}

// ---- per-graph mean ---------------------------------------------------------
__global__ void k_gsum(const int* __restrict__ gid, const u16* __restrict__ x,
                       float* __restrict__ gsum, float* __restrict__ gcnt){
    int tx = threadIdx.x;
    int n = blockIdx.x*2 + (tx >> 7);
    int c = tx & 127;
    int g = gid[n];
    atomicAdd(&gsum[g*HD + c], bf2f(x[(size_t)n*HD + c]));
    if(c == 0) atomicAdd(&gcnt[g], 1.f);
}

__global__ void k_gdiv(const float* __restrict__ gsum, const float* __restrict__ gcnt,
                       float* __restrict__ out){
    int i = blockIdx.x*256 + threadIdx.x;
    if(i >= NG*HD) return;
    out[i] = gsum[i] / fmaxf(gcnt[i/HD], 1.f);
}

extern "C" void kernel_launch(void* const* d_in, const int* in_sizes, int n_in,
                              void* d_out, int out_size, void* d_ws, size_t ws_size,
                              hipStream_t stream){
    const float* h     = (const float*)d_in[0];
    const int*   src   = (const int*)  d_in[1];
    const int*   dst   = (const int*)  d_in[2];
    const int*   gid   = (const int*)  d_in[3];
    const float* W0    = (const float*)d_in[4];
    const float* Wr    = (const float*)d_in[5];
    const float* att   = (const float*)d_in[6];
    const float* gamma = (const float*)d_in[7];
    const float* beta  = (const float*)d_in[8];
    const float* ow    = (const float*)d_in[9];

    char* p = (char*)d_ws;
    auto alloc = [&](size_t bytes) -> void* {
        void* q = (void*)p;
        p += (bytes + 255) & ~(size_t)255;
        return q;
    };
    u16*   z      = (u16*)  alloc((size_t)NN*NH*HD*2);   // 20.5 MB
    u16*   r      = (u16*)  alloc((size_t)NN*NH*HD*2);   // 20.5 MB
    u16*   x      = (u16*)  alloc((size_t)NN*HD*2);      // 5.1 MB
    float* es     = (float*)alloc((size_t)NN*NH*4);
    float* ed     = (float*)alloc((size_t)NN*NH*4);
    float* e4s    = (float*)alloc((size_t)NE*NH*4);      // 5.1 MB
    int*   counts = (int*)  alloc((size_t)NN*4);
    int*   rowptr = (int*)  alloc((size_t)(NN+1)*4);
    int*   cursor = (int*)  alloc((size_t)NN*4);
    int*   srcs   = (int*)  alloc((size_t)NE*4);
    int*   dsts   = (int*)  alloc((size_t)NE*4);
    float* bnsum  = (float*)alloc(1024*4);               // sums[512] + sqs[512]
    float* bnsqs  = bnsum + 512;
    float* bninv  = (float*)alloc(1024*4);               // inv[512] + shift[512]
    float* bnshift= bninv + 512;
    float* gsum   = (float*)alloc((size_t)(NG*HD + NG)*4);
    float* gcnt   = gsum + NG*HD;

    // CSR build (graph is identical both layers)
    hipMemsetAsync(counts, 0, (size_t)NN*4, stream);
    k_hist   <<<(NE+255)/256, 256, 0, stream>>>(dst, counts);
    k_scan   <<<1, 1024, 0, stream>>>(counts, rowptr, cursor);
    k_scatter<<<(NE+255)/256, 256, 0, stream>>>(src, dst, cursor, srcs, dsts);

    for(int j = 0; j < 2; ++j){
        if(j == 0) k_gemm< 74,false><<<dim3(NN/16, NH), 128, 0, stream>>>(h, nullptr, W0, z);
        else       k_gemm<128,true ><<<dim3(NN/16, NH), 128, 0, stream>>>(nullptr, x, Wr, z);

        k_dots     <<<NN/4, 256, 0, stream>>>(z, att + j*NH*2*HD, es, ed);
        k_elogits  <<<(NE+255)/256, 256, 0, stream>>>(srcs, dsts, es, ed, e4s);
        k_aggregate<<<NN, 256, 0, stream>>>(rowptr, srcs, e4s, z, r);

        hipMemsetAsync(bnsum, 0, 1024*4, stream);
        k_bnreduce <<<dim3(2,125), 256, 0, stream>>>(r, bnsum, bnsqs);
        k_bnfin    <<<2, 256, 0, stream>>>(bnsum, bnsqs, gamma + j*512, beta + j*512,
                                           bninv, bnshift);
        k_headmix  <<<NN/4, 256, 0, stream>>>(r, bninv, bnshift, ow + j*HD, x);
    }

    hipMemsetAsync(gsum, 0, (size_t)(NG*HD + NG)*4, stream);
    k_gsum<<<NN/2, 256, 0, stream>>>(gid, x, gsum, gcnt);
    k_gdiv<<<(NG*HD+255)/256, 256, 0, stream>>>(gsum, gcnt, (float*)d_out);
}

// Round 2
// 431.940 us; speedup vs baseline: 1.2288x; 1.2288x over previous
//
#include <hip/hip_runtime.h>
#include <hip/hip_bf16.h>

typedef unsigned short u16;
typedef unsigned int u32;

#define NN 20000      // nodes
#define NE 320000     // edges
#define NG 128        // graphs
#define HD 128        // hidden
#define NH 4          // heads
#define BN_EPS 1e-5f

__device__ __forceinline__ float bf2f(u16 v){ return __uint_as_float(((u32)v)<<16); }
__device__ __forceinline__ u16 f2bf(float f){
    u32 u = __float_as_uint(f);
    return (u16)((u + 0x7fffu + ((u>>16)&1u)) >> 16);   // RNE
}

// ---- CSR build -------------------------------------------------------------
__global__ void k_hist(const int* __restrict__ dst, int* __restrict__ counts){
    int e = blockIdx.x*256 + threadIdx.x;
    if(e < NE) atomicAdd(&counts[dst[e]], 1);
}

__global__ void k_scan(const int* __restrict__ counts, int* __restrict__ rowptr,
                       int* __restrict__ cursor){
    __shared__ int wsum[16];
    int tx = threadIdx.x, lane = tx & 63, wid = tx >> 6;
    int running = 0;
    for(int t = 0; t < (NN + 1023)/1024; ++t){
        int i = t*1024 + tx;
        int v = (i < NN) ? counts[i] : 0;
        int s = v;
        #pragma unroll
        for(int d = 1; d < 64; d <<= 1){ int o = __shfl_up(s, d); if(lane >= d) s += o; }
        if(lane == 63) wsum[wid] = s;
        __syncthreads();
        int woff = 0, total = 0;
        for(int w_ = 0; w_ < 16; ++w_){ int sw = wsum[w_]; total += sw; if(w_ < wid) woff += sw; }
        int ex = running + woff + s - v;   // exclusive prefix
        if(i < NN){ rowptr[i] = ex; cursor[i] = ex; }
        running += total;
        __syncthreads();
    }
    if(tx == 0) rowptr[NN] = running;
}

__global__ void k_scatter(const int* __restrict__ src, const int* __restrict__ dst,
                          int* __restrict__ cursor, int* __restrict__ srcs,
                          int* __restrict__ dsts){
    int e = blockIdx.x*256 + threadIdx.x;
    if(e >= NE) return;
    int d = dst[e];
    int p = atomicAdd(&cursor[d], 1);
    srcs[p] = src[e];
    dsts[p] = d;
}

// ---- z = x @ W per head (vector-ALU GEMM, 16-node tiles) -------------------
template<int K, bool BF16IN>
__global__ void k_gemm(const float* __restrict__ xf, const u16* __restrict__ xb,
                       const float* __restrict__ W, u16* __restrict__ z){
    __shared__ float xs[16][K];
    int h  = blockIdx.y;
    int n0 = blockIdx.x * 16;
    int tx = threadIdx.x;                     // 128 threads = out channel
    for(int idx = tx; idx < 16*K; idx += 128){
        int i = idx / K, k = idx - i*K;
        int n = n0 + i;
        xs[i][k] = BF16IN ? bf2f(xb[n*K + k]) : xf[n*K + k];
    }
    __syncthreads();
    float acc[16];
    #pragma unroll
    for(int i = 0; i < 16; ++i) acc[i] = 0.f;
    const float* Wh = W + h*(K*HD) + tx;
    for(int k = 0; k < K; ++k){
        float w = Wh[k*HD];
        #pragma unroll
        for(int i = 0; i < 16; ++i) acc[i] += xs[i][k]*w;
    }
    #pragma unroll
    for(int i = 0; i < 16; ++i)
        z[((n0+i)*NH + h)*HD + tx] = f2bf(acc[i]);
}

// ---- per-node attention dot products es = z.a_src, ed = z.a_dst ------------
__global__ void k_dots(const u16* __restrict__ z, const float* __restrict__ attj,
                       float* __restrict__ es, float* __restrict__ ed){
    int tx = threadIdx.x, lane = tx & 63, w = tx >> 6;
    int n = blockIdx.x*4 + w;
    if(n >= NN) return;
    int ch = lane*2;
    for(int h = 0; h < NH; ++h){
        u32 zz = *(const u32*)(z + (size_t)(n*NH + h)*HD + ch);
        float z0 = bf2f((u16)(zz & 0xffffu));
        float z1 = bf2f((u16)(zz >> 16));
        const float* a = attj + h*2*HD;
        float ps = z0*a[ch]    + z1*a[ch+1];
        float pd = z0*a[HD+ch] + z1*a[HD+ch+1];
        #pragma unroll
        for(int d = 32; d > 0; d >>= 1){ ps += __shfl_xor(ps, d); pd += __shfl_xor(pd, d); }
        if(lane == 0){ es[n*NH + h] = ps; ed[n*NH + h] = pd; }
    }
}

// ---- edge logits (sorted order), leaky_relu slope 0.01 ---------------------
__global__ void k_elogits(const int* __restrict__ srcs, const int* __restrict__ dsts,
                          const float* __restrict__ es, const float* __restrict__ ed,
                          float* __restrict__ e4s){
    int p = blockIdx.x*256 + threadIdx.x;
    if(p >= NE) return;
    int s = srcs[p], d = dsts[p];
    float4 a = *(const float4*)(es + s*4);
    float4 b = *(const float4*)(ed + d*4);
    float4 e;
    e.x = a.x + b.x; e.y = a.y + b.y; e.z = a.z + b.z; e.w = a.w + b.w;
    e.x = e.x >= 0.f ? e.x : 0.01f*e.x;
    e.y = e.y >= 0.f ? e.y : 0.01f*e.y;
    e.z = e.z >= 0.f ? e.z : 0.01f*e.z;
    e.w = e.w >= 0.f ? e.w : 0.01f*e.w;
    *(float4*)(e4s + p*4) = e;
}

// ---- segment softmax + weighted aggregation + relu -------------------------
// block = node, wave = head, 2 channels/lane
__global__ void k_aggregate(const int* __restrict__ rowptr, const int* __restrict__ srcs,
                            const float* __restrict__ e4s, const u16* __restrict__ z,
                            u16* __restrict__ r){
    int n = blockIdx.x;
    int tx = threadIdx.x, lane = tx & 63, h = tx >> 6;
    int p0 = rowptr[n], p1 = rowptr[n+1];
    int ch = lane*2;
    float acc0 = 0.f, acc1 = 0.f;
    if(p1 > p0){
        float m = -1e30f;
        for(int p = p0 + lane; p < p1; p += 64) m = fmaxf(m, e4s[p*4 + h]);
        #pragma unroll
        for(int d = 32; d > 0; d >>= 1) m = fmaxf(m, __shfl_xor(m, d));
        float s = 0.f;
        for(int p = p0 + lane; p < p1; p += 64) s += __expf(e4s[p*4 + h] - m);
        #pragma unroll
        for(int d = 32; d > 0; d >>= 1) s += __shfl_xor(s, d);
        float inv = 1.f/s;
        for(int p = p0; p < p1; ++p){
            float a = __expf(e4s[p*4 + h] - m) * inv;
            int sn = srcs[p];
            u32 zz = *(const u32*)(z + (size_t)(sn*NH + h)*HD + ch);
            acc0 += a * bf2f((u16)(zz & 0xffffu));
            acc1 += a * bf2f((u16)(zz >> 16));
        }
    }
    acc0 = fmaxf(acc0, 0.f);
    acc1 = fmaxf(acc1, 0.f);
    u32 out = (u32)f2bf(acc0) | ((u32)f2bf(acc1) << 16);
    *(u32*)(r + (size_t)(n*NH + h)*HD + ch) = out;
}

// ---- BatchNorm stats (sum, sumsq per channel) ------------------------------
__global__ void k_bnreduce(const u16* __restrict__ r, float* __restrict__ bnsum,
                           float* __restrict__ bnsqs){
    int c = blockIdx.x*256 + threadIdx.x;   // 0..511
    int nbeg = blockIdx.y * 160;            // 125 chunks * 160 = 20000
    float s = 0.f, s2 = 0.f;
    for(int i = 0; i < 160; ++i){
        float v = bf2f(r[(size_t)(nbeg+i)*512 + c]);
        s += v; s2 += v*v;
    }
    atomicAdd(&bnsum[c], s);
    atomicAdd(&bnsqs[c], s2);
}

__global__ void k_bnfin(const float* __restrict__ bnsum, const float* __restrict__ bnsqs,
                        const float* __restrict__ gamma, const float* __restrict__ beta,
                        float* __restrict__ inv, float* __restrict__ shift){
    int c = blockIdx.x*256 + threadIdx.x;
    if(c >= 512) return;
    float mean = bnsum[c] * (1.f/NN);
    float var  = bnsqs[c] * (1.f/NN) - mean*mean;
    float iv = gamma[c] * rsqrtf(var + BN_EPS);
    inv[c] = iv;
    shift[c] = beta[c] - mean*iv;
}

// ---- BN apply + head softmax mix -> x[N][128] ------------------------------
// out_b omitted: softmax(v + const) == softmax(v)
__global__ void k_headmix(const u16* __restrict__ r, const float* __restrict__ inv,
                          const float* __restrict__ shift, const float* __restrict__ ow,
                          u16* __restrict__ x){
    int tx = threadIdx.x, lane = tx & 63, w = tx >> 6;
    int n = blockIdx.x*4 + w;
    if(n >= NN) return;
    int ch = lane*2;
    float rn[NH][2];
    float sc[NH];
    #pragma unroll
    for(int h = 0; h < NH; ++h){
        int c = h*HD + ch;
        u32 zz = *(const u32*)(r + (size_t)n*512 + c);
        float v0 = bf2f((u16)(zz & 0xffffu))*inv[c]   + shift[c];
        float v1 = bf2f((u16)(zz >> 16))   *inv[c+1] + shift[c+1];
        rn[h][0] = v0; rn[h][1] = v1;
        float p = v0*ow[ch] + v1*ow[ch+1];
        #pragma unroll
        for(int d = 32; d > 0; d >>= 1) p += __shfl_xor(p, d);
        sc[h] = p;
    }
    float m = fmaxf(fmaxf(sc[0], sc[1]), fmaxf(sc[2], sc[3]));
    float e0 = __expf(sc[0]-m), e1 = __expf(sc[1]-m), e2 = __expf(sc[2]-m), e3 = __expf(sc[3]-m);
    float is = 1.f/(e0+e1+e2+e3);
    float x0 = (e0*rn[0][0] + e1*rn[1][0] + e2*rn[2][0] + e3*rn[3][0])*is;
    float x1 = (e0*rn[0][1] + e1*rn[1][1] + e2*rn[2][1] + e3*rn[3][1])*is;
    *(u32*)(x + (size_t)n*HD + ch) = (u32)f2bf(x0) | ((u32)f2bf(x1) << 16);
}

// ---- per-graph mean (graph_ids sorted -> contiguous ranges, no atomics) ----
// block = graph (128 blocks, 256 threads = 4 waves). Binary-search boundaries,
// stride nodes across waves, 64 lanes x u32 = 2 bf16 channels per lane.
__global__ void k_gmean(const int* __restrict__ gid, const u16* __restrict__ x,
                        float* __restrict__ out){
    int g = blockIdx.x;
    int tx = threadIdx.x, lane = tx & 63, w = tx >> 6;
    // lower_bound(gid, g) and lower_bound(gid, g+1)
    int lo = 0, hi = NN;
    while(lo < hi){ int mid = (lo + hi) >> 1; if(gid[mid] < g) lo = mid + 1; else hi = mid; }
    int start = lo;
    hi = NN;
    while(lo < hi){ int mid = (lo + hi) >> 1; if(gid[mid] < g + 1) lo = mid + 1; else hi = mid; }
    int end = lo;
    float a0 = 0.f, a1 = 0.f;
    for(int n = start + w; n < end; n += 4){
        u32 zz = *(const u32*)(x + (size_t)n*HD + lane*2);
        a0 += bf2f((u16)(zz & 0xffffu));
        a1 += bf2f((u16)(zz >> 16));
    }
    __shared__ float sm[4][HD];
    sm[w][lane*2]     = a0;
    sm[w][lane*2 + 1] = a1;
    __syncthreads();
    if(tx < HD){
        float s = sm[0][tx] + sm[1][tx] + sm[2][tx] + sm[3][tx];
        float cnt = (float)(end - start);
        out[g*HD + tx] = s / fmaxf(cnt, 1.f);
    }
}

extern "C" void kernel_launch(void* const* d_in, const int* in_sizes, int n_in,
                              void* d_out, int out_size, void* d_ws, size_t ws_size,
                              hipStream_t stream){
    const float* h     = (const float*)d_in[0];
    const int*   src   = (const int*)  d_in[1];
    const int*   dst   = (const int*)  d_in[2];
    const int*   gid   = (const int*)  d_in[3];
    const float* W0    = (const float*)d_in[4];
    const float* Wr    = (const float*)d_in[5];
    const float* att   = (const float*)d_in[6];
    const float* gamma = (const float*)d_in[7];
    const float* beta  = (const float*)d_in[8];
    const float* ow    = (const float*)d_in[9];

    char* p = (char*)d_ws;
    auto alloc = [&](size_t bytes) -> void* {
        void* q = (void*)p;
        p += (bytes + 255) & ~(size_t)255;
        return q;
    };
    u16*   z      = (u16*)  alloc((size_t)NN*NH*HD*2);   // 20.5 MB
    u16*   r      = (u16*)  alloc((size_t)NN*NH*HD*2);   // 20.5 MB
    u16*   x      = (u16*)  alloc((size_t)NN*HD*2);      // 5.1 MB
    float* es     = (float*)alloc((size_t)NN*NH*4);
    float* ed     = (float*)alloc((size_t)NN*NH*4);
    float* e4s    = (float*)alloc((size_t)NE*NH*4);      // 5.1 MB
    int*   counts = (int*)  alloc((size_t)NN*4);
    int*   rowptr = (int*)  alloc((size_t)(NN+1)*4);
    int*   cursor = (int*)  alloc((size_t)NN*4);
    int*   srcs   = (int*)  alloc((size_t)NE*4);
    int*   dsts   = (int*)  alloc((size_t)NE*4);
    float* bnsum  = (float*)alloc(1024*4);               // sums[512] + sqs[512]
    float* bnsqs  = bnsum + 512;
    float* bninv  = (float*)alloc(1024*4);               // inv[512] + shift[512]
    float* bnshift= bninv + 512;

    // CSR build (graph is identical both layers)
    hipMemsetAsync(counts, 0, (size_t)NN*4, stream);
    k_hist   <<<(NE+255)/256, 256, 0, stream>>>(dst, counts);
    k_scan   <<<1, 1024, 0, stream>>>(counts, rowptr, cursor);
    k_scatter<<<(NE+255)/256, 256, 0, stream>>>(src, dst, cursor, srcs, dsts);

    for(int j = 0; j < 2; ++j){
        if(j == 0) k_gemm< 74,false><<<dim3(NN/16, NH), 128, 0, stream>>>(h, nullptr, W0, z);
        else       k_gemm<128,true ><<<dim3(NN/16, NH), 128, 0, stream>>>(nullptr, x, Wr, z);

        k_dots     <<<NN/4, 256, 0, stream>>>(z, att + j*NH*2*HD, es, ed);
        k_elogits  <<<(NE+255)/256, 256, 0, stream>>>(srcs, dsts, es, ed, e4s);
        k_aggregate<<<NN, 256, 0, stream>>>(rowptr, srcs, e4s, z, r);

        hipMemsetAsync(bnsum, 0, 1024*4, stream);
        k_bnreduce <<<dim3(2,125), 256, 0, stream>>>(r, bnsum, bnsqs);
        k_bnfin    <<<2, 256, 0, stream>>>(bnsum, bnsqs, gamma + j*512, beta + j*512,
                                           bninv, bnshift);
        k_headmix  <<<NN/4, 256, 0, stream>>>(r, bninv, bnshift, ow + j*HD, x);
    }

    k_gmean<<<NG, 256, 0, stream>>>(gid, x, (float*)d_out);
}

// Round 3
// 413.902 us; speedup vs baseline: 1.2823x; 1.0436x over previous
//
#include <hip/hip_runtime.h>
#include <hip/hip_bf16.h>

typedef unsigned short u16;
typedef unsigned int u32;

#define NN 20000      // nodes
#define NE 320000     // edges
#define NG 128        // graphs
#define HD 128        // hidden
#define NH 4          // heads
#define BN_EPS 1e-5f

__device__ __forceinline__ float bf2f(u16 v){ return __uint_as_float(((u32)v)<<16); }
__device__ __forceinline__ u16 f2bf(float f){
    u32 u = __float_as_uint(f);
    return (u16)((u + 0x7fffu + ((u>>16)&1u)) >> 16);   // RNE
}

// ---- CSR build -------------------------------------------------------------
__global__ void k_hist(const int* __restrict__ dst, int* __restrict__ counts){
    int e = blockIdx.x*256 + threadIdx.x;
    if(e < NE) atomicAdd(&counts[dst[e]], 1);
}

__global__ void k_scan(const int* __restrict__ counts, int* __restrict__ rowptr,
                       int* __restrict__ cursor){
    __shared__ int wsum[16];
    int tx = threadIdx.x, lane = tx & 63, wid = tx >> 6;
    int running = 0;
    for(int t = 0; t < (NN + 1023)/1024; ++t){
        int i = t*1024 + tx;
        int v = (i < NN) ? counts[i] : 0;
        int s = v;
        #pragma unroll
        for(int d = 1; d < 64; d <<= 1){ int o = __shfl_up(s, d); if(lane >= d) s += o; }
        if(lane == 63) wsum[wid] = s;
        __syncthreads();
        int woff = 0, total = 0;
        for(int w_ = 0; w_ < 16; ++w_){ int sw = wsum[w_]; total += sw; if(w_ < wid) woff += sw; }
        int ex = running + woff + s - v;   // exclusive prefix
        if(i < NN){ rowptr[i] = ex; cursor[i] = ex; }
        running += total;
        __syncthreads();
    }
    if(tx == 0) rowptr[NN] = running;
}

__global__ void k_scatter(const int* __restrict__ src, const int* __restrict__ dst,
                          int* __restrict__ cursor, int* __restrict__ srcs){
    int e = blockIdx.x*256 + threadIdx.x;
    if(e >= NE) return;
    int d = dst[e];
    int p = atomicAdd(&cursor[d], 1);
    srcs[p] = src[e];
}

// ---- z = x @ W per head (vector-ALU GEMM, 16-node tiles) -------------------
template<int K, bool BF16IN>
__global__ void k_gemm(const float* __restrict__ xf, const u16* __restrict__ xb,
                       const float* __restrict__ W, u16* __restrict__ z){
    __shared__ float xs[16][K];
    int h  = blockIdx.y;
    int n0 = blockIdx.x * 16;
    int tx = threadIdx.x;                     // 128 threads = out channel
    for(int idx = tx; idx < 16*K; idx += 128){
        int i = idx / K, k = idx - i*K;
        int n = n0 + i;
        xs[i][k] = BF16IN ? bf2f(xb[n*K + k]) : xf[n*K + k];
    }
    __syncthreads();
    float acc[16];
    #pragma unroll
    for(int i = 0; i < 16; ++i) acc[i] = 0.f;
    const float* Wh = W + h*(K*HD) + tx;
    for(int k = 0; k < K; ++k){
        float w = Wh[k*HD];
        #pragma unroll
        for(int i = 0; i < 16; ++i) acc[i] += xs[i][k]*w;
    }
    #pragma unroll
    for(int i = 0; i < 16; ++i)
        z[((n0+i)*NH + h)*HD + tx] = f2bf(acc[i]);
}

// ---- per-node attention dot products es = z.a_src, ed = z.a_dst ------------
__global__ void k_dots(const u16* __restrict__ z, const float* __restrict__ attj,
                       float* __restrict__ es, float* __restrict__ ed){
    int tx = threadIdx.x, lane = tx & 63, w = tx >> 6;
    int n = blockIdx.x*4 + w;
    if(n >= NN) return;
    int ch = lane*2;
    for(int h = 0; h < NH; ++h){
        u32 zz = *(const u32*)(z + (size_t)(n*NH + h)*HD + ch);
        float z0 = bf2f((u16)(zz & 0xffffu));
        float z1 = bf2f((u16)(zz >> 16));
        const float* a = attj + h*2*HD;
        float ps = z0*a[ch]    + z1*a[ch+1];
        float pd = z0*a[HD+ch] + z1*a[HD+ch+1];
        #pragma unroll
        for(int d = 32; d > 0; d >>= 1){ ps += __shfl_xor(ps, d); pd += __shfl_xor(pd, d); }
        if(lane == 0){ es[n*NH + h] = ps; ed[n*NH + h] = pd; }
    }
}

// ---- fused edge-logit + segment softmax + weighted aggregation + relu ------
// block = node, wave = head, 2 channels/lane. Single pass, no max subtraction
// (softmax shift-invariant; |e| << 88 so exp cannot overflow).
// Per 64-edge chunk: lane-parallel {srcs load, es gather, leaky, exp}; then a
// serial gather loop broadcasting (ex, src) from lane i via __shfl (uniform i).
__global__ void k_aggregate(const int* __restrict__ rowptr, const int* __restrict__ srcs,
                            const float* __restrict__ es, const float* __restrict__ ed,
                            const u16* __restrict__ z, u16* __restrict__ r){
    int n = blockIdx.x;
    int tx = threadIdx.x, lane = tx & 63, h = tx >> 6;
    int p0 = rowptr[n], p1 = rowptr[n+1];
    int ch = lane*2;
    float edn = ed[n*NH + h];
    float ssum = 0.f, acc0 = 0.f, acc1 = 0.f;
    for(int base = p0; base < p1; base += 64){
        int p = base + lane;
        int sn = 0; float ex = 0.f;
        if(p < p1){
            sn = srcs[p];
            float e = es[sn*NH + h] + edn;
            e = e >= 0.f ? e : 0.01f*e;          // leaky_relu, slope 0.01
            ex = __expf(e);
        }
        ssum += ex;
        int cnt = min(64, p1 - base);
        for(int i = 0; i < cnt; ++i){
            float a  = __shfl(ex, i);
            int   sj = __shfl(sn, i);
            u32 zz = *(const u32*)(z + (size_t)(sj*NH + h)*HD + ch);
            acc0 += a * bf2f((u16)(zz & 0xffffu));
            acc1 += a * bf2f((u16)(zz >> 16));
        }
    }
    #pragma unroll
    for(int d = 32; d > 0; d >>= 1) ssum += __shfl_xor(ssum, d);
    float inv = (ssum > 0.f) ? 1.f/ssum : 0.f;
    acc0 = fmaxf(acc0*inv, 0.f);
    acc1 = fmaxf(acc1*inv, 0.f);
    *(u32*)(r + (size_t)(n*NH + h)*HD + ch) = (u32)f2bf(acc0) | ((u32)f2bf(acc1) << 16);
}

// ---- BatchNorm stats (sum, sumsq per channel) ------------------------------
__global__ void k_bnreduce(const u16* __restrict__ r, float* __restrict__ bnsum,
                           float* __restrict__ bnsqs){
    int c = blockIdx.x*256 + threadIdx.x;   // 0..511
    int nbeg = blockIdx.y * 160;            // 125 chunks * 160 = 20000
    float s = 0.f, s2 = 0.f;
    for(int i = 0; i < 160; ++i){
        float v = bf2f(r[(size_t)(nbeg+i)*512 + c]);
        s += v; s2 += v*v;
    }
    atomicAdd(&bnsum[c], s);
    atomicAdd(&bnsqs[c], s2);
}

__global__ void k_bnfin(const float* __restrict__ bnsum, const float* __restrict__ bnsqs,
                        const float* __restrict__ gamma, const float* __restrict__ beta,
                        float* __restrict__ inv, float* __restrict__ shift){
    int c = blockIdx.x*256 + threadIdx.x;
    if(c >= 512) return;
    float mean = bnsum[c] * (1.f/NN);
    float var  = bnsqs[c] * (1.f/NN) - mean*mean;
    float iv = gamma[c] * rsqrtf(var + BN_EPS);
    inv[c] = iv;
    shift[c] = beta[c] - mean*iv;
}

// ---- BN apply + head softmax mix -> x[N][128] ------------------------------
// out_b omitted: softmax(v + const) == softmax(v)
__global__ void k_headmix(const u16* __restrict__ r, const float* __restrict__ inv,
                          const float* __restrict__ shift, const float* __restrict__ ow,
                          u16* __restrict__ x){
    int tx = threadIdx.x, lane = tx & 63, w = tx >> 6;
    int n = blockIdx.x*4 + w;
    if(n >= NN) return;
    int ch = lane*2;
    float rn[NH][2];
    float sc[NH];
    #pragma unroll
    for(int h = 0; h < NH; ++h){
        int c = h*HD + ch;
        u32 zz = *(const u32*)(r + (size_t)n*512 + c);
        float v0 = bf2f((u16)(zz & 0xffffu))*inv[c]   + shift[c];
        float v1 = bf2f((u16)(zz >> 16))   *inv[c+1] + shift[c+1];
        rn[h][0] = v0; rn[h][1] = v1;
        float p = v0*ow[ch] + v1*ow[ch+1];
        #pragma unroll
        for(int d = 32; d > 0; d >>= 1) p += __shfl_xor(p, d);
        sc[h] = p;
    }
    float m = fmaxf(fmaxf(sc[0], sc[1]), fmaxf(sc[2], sc[3]));
    float e0 = __expf(sc[0]-m), e1 = __expf(sc[1]-m), e2 = __expf(sc[2]-m), e3 = __expf(sc[3]-m);
    float is = 1.f/(e0+e1+e2+e3);
    float x0 = (e0*rn[0][0] + e1*rn[1][0] + e2*rn[2][0] + e3*rn[3][0])*is;
    float x1 = (e0*rn[0][1] + e1*rn[1][1] + e2*rn[2][1] + e3*rn[3][1])*is;
    *(u32*)(x + (size_t)n*HD + ch) = (u32)f2bf(x0) | ((u32)f2bf(x1) << 16);
}

// ---- per-graph mean (graph_ids sorted -> contiguous ranges, no atomics) ----
__global__ void k_gmean(const int* __restrict__ gid, const u16* __restrict__ x,
                        float* __restrict__ out){
    int g = blockIdx.x;
    int tx = threadIdx.x, lane = tx & 63, w = tx >> 6;
    int lo = 0, hi = NN;
    while(lo < hi){ int mid = (lo + hi) >> 1; if(gid[mid] < g) lo = mid + 1; else hi = mid; }
    int start = lo;
    hi = NN;
    while(lo < hi){ int mid = (lo + hi) >> 1; if(gid[mid] < g + 1) lo = mid + 1; else hi = mid; }
    int end = lo;
    float a0 = 0.f, a1 = 0.f;
    for(int n = start + w; n < end; n += 4){
        u32 zz = *(const u32*)(x + (size_t)n*HD + lane*2);
        a0 += bf2f((u16)(zz & 0xffffu));
        a1 += bf2f((u16)(zz >> 16));
    }
    __shared__ float sm[4][HD];
    sm[w][lane*2]     = a0;
    sm[w][lane*2 + 1] = a1;
    __syncthreads();
    if(tx < HD){
        float s = sm[0][tx] + sm[1][tx] + sm[2][tx] + sm[3][tx];
        float cnt = (float)(end - start);
        out[g*HD + tx] = s / fmaxf(cnt, 1.f);
    }
}

extern "C" void kernel_launch(void* const* d_in, const int* in_sizes, int n_in,
                              void* d_out, int out_size, void* d_ws, size_t ws_size,
                              hipStream_t stream){
    const float* h     = (const float*)d_in[0];
    const int*   src   = (const int*)  d_in[1];
    const int*   dst   = (const int*)  d_in[2];
    const int*   gid   = (const int*)  d_in[3];
    const float* W0    = (const float*)d_in[4];
    const float* Wr    = (const float*)d_in[5];
    const float* att   = (const float*)d_in[6];
    const float* gamma = (const float*)d_in[7];
    const float* beta  = (const float*)d_in[8];
    const float* ow    = (const float*)d_in[9];

    char* p = (char*)d_ws;
    auto alloc = [&](size_t bytes) -> void* {
        void* q = (void*)p;
        p += (bytes + 255) & ~(size_t)255;
        return q;
    };
    u16*   z      = (u16*)  alloc((size_t)NN*NH*HD*2);   // 20.5 MB
    u16*   r      = (u16*)  alloc((size_t)NN*NH*HD*2);   // 20.5 MB
    u16*   x      = (u16*)  alloc((size_t)NN*HD*2);      // 5.1 MB
    float* es     = (float*)alloc((size_t)NN*NH*4);
    float* ed     = (float*)alloc((size_t)NN*NH*4);
    int*   counts = (int*)  alloc((size_t)NN*4);
    int*   rowptr = (int*)  alloc((size_t)(NN+1)*4);
    int*   cursor = (int*)  alloc((size_t)NN*4);
    int*   srcs   = (int*)  alloc((size_t)NE*4);
    float* bnsum  = (float*)alloc(1024*4);               // sums[512] + sqs[512]
    float* bnsqs  = bnsum + 512;
    float* bninv  = (float*)alloc(1024*4);               // inv[512] + shift[512]
    float* bnshift= bninv + 512;

    // CSR build (graph is identical both layers)
    hipMemsetAsync(counts, 0, (size_t)NN*4, stream);
    k_hist   <<<(NE+255)/256, 256, 0, stream>>>(dst, counts);
    k_scan   <<<1, 1024, 0, stream>>>(counts, rowptr, cursor);
    k_scatter<<<(NE+255)/256, 256, 0, stream>>>(src, dst, cursor, srcs);

    for(int j = 0; j < 2; ++j){
        if(j == 0) k_gemm< 74,false><<<dim3(NN/16, NH), 128, 0, stream>>>(h, nullptr, W0, z);
        else       k_gemm<128,true ><<<dim3(NN/16, NH), 128, 0, stream>>>(nullptr, x, Wr, z);

        k_dots     <<<NN/4, 256, 0, stream>>>(z, att + j*NH*2*HD, es, ed);
        k_aggregate<<<NN, 256, 0, stream>>>(rowptr, srcs, es, ed, z, r);

        hipMemsetAsync(bnsum, 0, 1024*4, stream);
        k_bnreduce <<<dim3(2,125), 256, 0, stream>>>(r, bnsum, bnsqs);
        k_bnfin    <<<2, 256, 0, stream>>>(bnsum, bnsqs, gamma + j*512, beta + j*512,
                                           bninv, bnshift);
        k_headmix  <<<NN/4, 256, 0, stream>>>(r, bninv, bnshift, ow + j*HD, x);
    }

    k_gmean<<<NG, 256, 0, stream>>>(gid, x, (float*)d_out);
}

// Round 4
// 347.135 us; speedup vs baseline: 1.5289x; 1.1923x over previous
//
#include <hip/hip_runtime.h>
#include <hip/hip_bf16.h>

typedef unsigned short u16;
typedef unsigned int u32;

#define NN 20000      // nodes
#define NE 320000     // edges
#define NG 128        // graphs
#define HD 128        // hidden
#define NH 4          // heads
#define BN_EPS 1e-5f

__device__ __forceinline__ float bf2f(u16 v){ return __uint_as_float(((u32)v)<<16); }
__device__ __forceinline__ float bflo(u32 v){ return __uint_as_float(v<<16); }
__device__ __forceinline__ float bfhi(u32 v){ return __uint_as_float(v & 0xffff0000u); }
__device__ __forceinline__ u16 f2bf(float f){
    u32 u = __float_as_uint(f);
    return (u16)((u + 0x7fffu + ((u>>16)&1u)) >> 16);   // RNE
}
__device__ __forceinline__ u32 pack2(float a, float b){
    return (u32)f2bf(a) | ((u32)f2bf(b) << 16);
}

// ---- CSR build -------------------------------------------------------------
__global__ void k_hist(const int* __restrict__ dst, int* __restrict__ counts){
    int e = blockIdx.x*256 + threadIdx.x;
    if(e < NE) atomicAdd(&counts[dst[e]], 1);
}

__global__ void k_scan(const int* __restrict__ counts, int* __restrict__ rowptr,
                       int* __restrict__ cursor){
    __shared__ int wsum[16];
    int tx = threadIdx.x, lane = tx & 63, wid = tx >> 6;
    int running = 0;
    for(int t = 0; t < (NN + 1023)/1024; ++t){
        int i = t*1024 + tx;
        int v = (i < NN) ? counts[i] : 0;
        int s = v;
        #pragma unroll
        for(int d = 1; d < 64; d <<= 1){ int o = __shfl_up(s, d); if(lane >= d) s += o; }
        if(lane == 63) wsum[wid] = s;
        __syncthreads();
        int woff = 0, total = 0;
        for(int w_ = 0; w_ < 16; ++w_){ int sw = wsum[w_]; total += sw; if(w_ < wid) woff += sw; }
        int ex = running + woff + s - v;   // exclusive prefix
        if(i < NN){ rowptr[i] = ex; cursor[i] = ex; }
        running += total;
        __syncthreads();
    }
    if(tx == 0) rowptr[NN] = running;
}

__global__ void k_scatter(const int* __restrict__ src, const int* __restrict__ dst,
                          int* __restrict__ cursor, int* __restrict__ srcs){
    int e = blockIdx.x*256 + threadIdx.x;
    if(e >= NE) return;
    int d = dst[e];
    int p = atomicAdd(&cursor[d], 1);
    srcs[p] = src[e];
}

// ---- z = x @ W per head (vector-ALU GEMM, 16-node tiles) -------------------
template<int K, bool BF16IN>
__global__ void k_gemm(const float* __restrict__ xf, const u16* __restrict__ xb,
                       const float* __restrict__ W, u16* __restrict__ z){
    __shared__ float xs[16][K];
    int h  = blockIdx.y;
    int n0 = blockIdx.x * 16;
    int tx = threadIdx.x;                     // 128 threads = out channel
    for(int idx = tx; idx < 16*K; idx += 128){
        int i = idx / K, k = idx - i*K;
        int n = n0 + i;
        xs[i][k] = BF16IN ? bf2f(xb[n*K + k]) : xf[n*K + k];
    }
    __syncthreads();
    float acc[16];
    #pragma unroll
    for(int i = 0; i < 16; ++i) acc[i] = 0.f;
    const float* Wh = W + h*(K*HD) + tx;
    for(int k = 0; k < K; ++k){
        float w = Wh[k*HD];
        #pragma unroll
        for(int i = 0; i < 16; ++i) acc[i] += xs[i][k]*w;
    }
    #pragma unroll
    for(int i = 0; i < 16; ++i)
        z[((n0+i)*NH + h)*HD + tx] = f2bf(acc[i]);
}

// ---- per-node attention dot products es = z.a_src, ed = z.a_dst ------------
__global__ void k_dots(const u16* __restrict__ z, const float* __restrict__ attj,
                       float* __restrict__ es, float* __restrict__ ed){
    int tx = threadIdx.x, lane = tx & 63, w = tx >> 6;
    int n = blockIdx.x*4 + w;
    if(n >= NN) return;
    int ch = lane*2;
    for(int h = 0; h < NH; ++h){
        u32 zz = *(const u32*)(z + (size_t)(n*NH + h)*HD + ch);
        float z0 = bflo(zz);
        float z1 = bfhi(zz);
        const float* a = attj + h*2*HD;
        float ps = z0*a[ch]    + z1*a[ch+1];
        float pd = z0*a[HD+ch] + z1*a[HD+ch+1];
        #pragma unroll
        for(int d = 32; d > 0; d >>= 1){ ps += __shfl_xor(ps, d); pd += __shfl_xor(pd, d); }
        if(lane == 0){ es[n*NH + h] = ps; ed[n*NH + h] = pd; }
    }
}

// ---- fused edge-logit + segment softmax + weighted aggregation + relu ------
// block = node, wave = head. Lane = (edge_slot 0..3, channel_group 0..15).
// Per inner iteration: 8 edges via TWO independent dwordx4 loads per lane
// (each load = 4 edge-slots x 16 lanes x 16B = full 256B row per edge) ->
// ~2KB in flight per wave (vs 256B before): latency -> bandwidth bound.
// No max subtraction (softmax shift-invariant, |logit| << 88).
__global__ void k_aggregate(const int* __restrict__ rowptr, const int* __restrict__ srcs,
                            const float* __restrict__ es, const float* __restrict__ ed,
                            const u16* __restrict__ z, u16* __restrict__ r){
    int n = blockIdx.x;
    int tx = threadIdx.x, lane = tx & 63, h = tx >> 6;
    int p0 = rowptr[n], p1 = rowptr[n+1];
    int eslot = lane >> 4;       // 0..3
    int cidx  = lane & 15;       // 8 channels each: cidx*8 .. cidx*8+7
    float edn = ed[n*NH + h];
    float ssum = 0.f;
    float acc[8];
    #pragma unroll
    for(int k = 0; k < 8; ++k) acc[k] = 0.f;

    for(int base = p0; base < p1; base += 64){
        int p = base + lane;
        int sn = 0; float ex = 0.f;
        if(p < p1){
            sn = srcs[p];
            float e = es[sn*NH + h] + edn;
            e = e >= 0.f ? e : 0.01f*e;          // leaky_relu, slope 0.01
            ex = __expf(e);
        }
        ssum += ex;
        int cnt = min(64, p1 - base);
        int niter = (cnt + 7) >> 3;              // 8 edges per iteration
        for(int i = 0; i < niter; ++i){
            int e0 = i*8 + eslot;                // <= 63
            int e1 = e0 + 4;                     // <= 63 (ex==0 past cnt)
            float a0 = __shfl(ex, e0);
            int   s0 = __shfl(sn, e0);
            float a1 = __shfl(ex, e1);
            int   s1 = __shfl(sn, e1);
            const uint4* q0 = (const uint4*)(z + (s0*NH + h)*HD + cidx*8);
            const uint4* q1 = (const uint4*)(z + (s1*NH + h)*HD + cidx*8);
            uint4 v0 = *q0;
            uint4 v1 = *q1;
            acc[0] += a0*bflo(v0.x); acc[1] += a0*bfhi(v0.x);
            acc[2] += a0*bflo(v0.y); acc[3] += a0*bfhi(v0.y);
            acc[4] += a0*bflo(v0.z); acc[5] += a0*bfhi(v0.z);
            acc[6] += a0*bflo(v0.w); acc[7] += a0*bfhi(v0.w);
            acc[0] += a1*bflo(v1.x); acc[1] += a1*bfhi(v1.x);
            acc[2] += a1*bflo(v1.y); acc[3] += a1*bfhi(v1.y);
            acc[4] += a1*bflo(v1.z); acc[5] += a1*bfhi(v1.z);
            acc[6] += a1*bflo(v1.w); acc[7] += a1*bfhi(v1.w);
        }
    }
    // combine edge-slots (after xor 16 and 32, every lane holds the full sum)
    #pragma unroll
    for(int k = 0; k < 8; ++k){
        acc[k] += __shfl_xor(acc[k], 16);
        acc[k] += __shfl_xor(acc[k], 32);
    }
    #pragma unroll
    for(int d = 32; d > 0; d >>= 1) ssum += __shfl_xor(ssum, d);
    float inv = (ssum > 0.f) ? 1.f/ssum : 0.f;
    if(eslot == 0){
        float c0 = fmaxf(acc[0]*inv, 0.f), c1 = fmaxf(acc[1]*inv, 0.f);
        float c2 = fmaxf(acc[2]*inv, 0.f), c3 = fmaxf(acc[3]*inv, 0.f);
        float c4 = fmaxf(acc[4]*inv, 0.f), c5 = fmaxf(acc[5]*inv, 0.f);
        float c6 = fmaxf(acc[6]*inv, 0.f), c7 = fmaxf(acc[7]*inv, 0.f);
        uint4 o;
        o.x = pack2(c0, c1); o.y = pack2(c2, c3);
        o.z = pack2(c4, c5); o.w = pack2(c6, c7);
        *(uint4*)(r + (n*NH + h)*HD + cidx*8) = o;
    }
}

// ---- BatchNorm stats (sum, sumsq per channel) ------------------------------
__global__ void k_bnreduce(const u16* __restrict__ r, float* __restrict__ bnsum,
                           float* __restrict__ bnsqs){
    int c = blockIdx.x*256 + threadIdx.x;   // 0..511
    int nbeg = blockIdx.y * 160;            // 125 chunks * 160 = 20000
    float s = 0.f, s2 = 0.f;
    for(int i = 0; i < 160; ++i){
        float v = bf2f(r[(size_t)(nbeg+i)*512 + c]);
        s += v; s2 += v*v;
    }
    atomicAdd(&bnsum[c], s);
    atomicAdd(&bnsqs[c], s2);
}

__global__ void k_bnfin(const float* __restrict__ bnsum, const float* __restrict__ bnsqs,
                        const float* __restrict__ gamma, const float* __restrict__ beta,
                        float* __restrict__ inv, float* __restrict__ shift){
    int c = blockIdx.x*256 + threadIdx.x;
    if(c >= 512) return;
    float mean = bnsum[c] * (1.f/NN);
    float var  = bnsqs[c] * (1.f/NN) - mean*mean;
    float iv = gamma[c] * rsqrtf(var + BN_EPS);
    inv[c] = iv;
    shift[c] = beta[c] - mean*iv;
}

// ---- BN apply + head softmax mix -> x[N][128] ------------------------------
// out_b omitted: softmax(v + const) == softmax(v)
__global__ void k_headmix(const u16* __restrict__ r, const float* __restrict__ inv,
                          const float* __restrict__ shift, const float* __restrict__ ow,
                          u16* __restrict__ x){
    int tx = threadIdx.x, lane = tx & 63, w = tx >> 6;
    int n = blockIdx.x*4 + w;
    if(n >= NN) return;
    int ch = lane*2;
    float rn[NH][2];
    float sc[NH];
    #pragma unroll
    for(int h = 0; h < NH; ++h){
        int c = h*HD + ch;
        u32 zz = *(const u32*)(r + (size_t)n*512 + c);
        float v0 = bflo(zz)*inv[c]   + shift[c];
        float v1 = bfhi(zz)*inv[c+1] + shift[c+1];
        rn[h][0] = v0; rn[h][1] = v1;
        float p = v0*ow[ch] + v1*ow[ch+1];
        #pragma unroll
        for(int d = 32; d > 0; d >>= 1) p += __shfl_xor(p, d);
        sc[h] = p;
    }
    float m = fmaxf(fmaxf(sc[0], sc[1]), fmaxf(sc[2], sc[3]));
    float e0 = __expf(sc[0]-m), e1 = __expf(sc[1]-m), e2 = __expf(sc[2]-m), e3 = __expf(sc[3]-m);
    float is = 1.f/(e0+e1+e2+e3);
    float x0 = (e0*rn[0][0] + e1*rn[1][0] + e2*rn[2][0] + e3*rn[3][0])*is;
    float x1 = (e0*rn[0][1] + e1*rn[1][1] + e2*rn[2][1] + e3*rn[3][1])*is;
    *(u32*)(x + (size_t)n*HD + ch) = pack2(x0, x1);
}

// ---- per-graph mean (graph_ids sorted -> contiguous ranges, no atomics) ----
__global__ void k_gmean(const int* __restrict__ gid, const u16* __restrict__ x,
                        float* __restrict__ out){
    int g = blockIdx.x;
    int tx = threadIdx.x, lane = tx & 63, w = tx >> 6;
    int lo = 0, hi = NN;
    while(lo < hi){ int mid = (lo + hi) >> 1; if(gid[mid] < g) lo = mid + 1; else hi = mid; }
    int start = lo;
    hi = NN;
    while(lo < hi){ int mid = (lo + hi) >> 1; if(gid[mid] < g + 1) lo = mid + 1; else hi = mid; }
    int end = lo;
    float a0 = 0.f, a1 = 0.f;
    for(int n = start + w; n < end; n += 4){
        u32 zz = *(const u32*)(x + (size_t)n*HD + lane*2);
        a0 += bflo(zz);
        a1 += bfhi(zz);
    }
    __shared__ float sm[4][HD];
    sm[w][lane*2]     = a0;
    sm[w][lane*2 + 1] = a1;
    __syncthreads();
    if(tx < HD){
        float s = sm[0][tx] + sm[1][tx] + sm[2][tx] + sm[3][tx];
        float cnt = (float)(end - start);
        out[g*HD + tx] = s / fmaxf(cnt, 1.f);
    }
}

extern "C" void kernel_launch(void* const* d_in, const int* in_sizes, int n_in,
                              void* d_out, int out_size, void* d_ws, size_t ws_size,
                              hipStream_t stream){
    const float* h     = (const float*)d_in[0];
    const int*   src   = (const int*)  d_in[1];
    const int*   dst   = (const int*)  d_in[2];
    const int*   gid   = (const int*)  d_in[3];
    const float* W0    = (const float*)d_in[4];
    const float* Wr    = (const float*)d_in[5];
    const float* att   = (const float*)d_in[6];
    const float* gamma = (const float*)d_in[7];
    const float* beta  = (const float*)d_in[8];
    const float* ow    = (const float*)d_in[9];

    char* p = (char*)d_ws;
    auto alloc = [&](size_t bytes) -> void* {
        void* q = (void*)p;
        p += (bytes + 255) & ~(size_t)255;
        return q;
    };
    u16*   z      = (u16*)  alloc((size_t)NN*NH*HD*2);   // 20.5 MB
    u16*   r      = (u16*)  alloc((size_t)NN*NH*HD*2);   // 20.5 MB
    u16*   x      = (u16*)  alloc((size_t)NN*HD*2);      // 5.1 MB
    float* es     = (float*)alloc((size_t)NN*NH*4);
    float* ed     = (float*)alloc((size_t)NN*NH*4);
    int*   counts = (int*)  alloc((size_t)NN*4);
    int*   rowptr = (int*)  alloc((size_t)(NN+1)*4);
    int*   cursor = (int*)  alloc((size_t)NN*4);
    int*   srcs   = (int*)  alloc((size_t)NE*4);
    float* bnsum  = (float*)alloc(1024*4);               // sums[512] + sqs[512]
    float* bnsqs  = bnsum + 512;
    float* bninv  = (float*)alloc(1024*4);               // inv[512] + shift[512]
    float* bnshift= bninv + 512;

    // CSR build (graph is identical both layers)
    hipMemsetAsync(counts, 0, (size_t)NN*4, stream);
    k_hist   <<<(NE+255)/256, 256, 0, stream>>>(dst, counts);
    k_scan   <<<1, 1024, 0, stream>>>(counts, rowptr, cursor);
    k_scatter<<<(NE+255)/256, 256, 0, stream>>>(src, dst, cursor, srcs);

    for(int j = 0; j < 2; ++j){
        if(j == 0) k_gemm< 74,false><<<dim3(NN/16, NH), 128, 0, stream>>>(h, nullptr, W0, z);
        else       k_gemm<128,true ><<<dim3(NN/16, NH), 128, 0, stream>>>(nullptr, x, Wr, z);

        k_dots     <<<NN/4, 256, 0, stream>>>(z, att + j*NH*2*HD, es, ed);
        k_aggregate<<<NN, 256, 0, stream>>>(rowptr, srcs, es, ed, z, r);

        hipMemsetAsync(bnsum, 0, 1024*4, stream);
        k_bnreduce <<<dim3(2,125), 256, 0, stream>>>(r, bnsum, bnsqs);
        k_bnfin    <<<2, 256, 0, stream>>>(bnsum, bnsqs, gamma + j*512, beta + j*512,
                                           bninv, bnshift);
        k_headmix  <<<NN/4, 256, 0, stream>>>(r, bninv, bnshift, ow + j*HD, x);
    }

    k_gmean<<<NG, 256, 0, stream>>>(gid, x, (float*)d_out);
}

// Round 5
// 291.973 us; speedup vs baseline: 1.8178x; 1.1889x over previous
//
#include <hip/hip_runtime.h>
#include <hip/hip_bf16.h>

typedef unsigned short u16;
typedef unsigned int u32;
typedef __attribute__((ext_vector_type(8))) short bf16x8;
typedef __attribute__((ext_vector_type(4))) float f32x4;

#define NN 20000      // nodes
#define NE 320000     // edges
#define NG 128        // graphs
#define HD 128        // hidden
#define NH 4          // heads
#define KIN 74        // input features
#define KP0 96        // KIN padded to multiple of 32
#define BN_EPS 1e-5f

__device__ __forceinline__ float bf2f(u16 v){ return __uint_as_float(((u32)v)<<16); }
__device__ __forceinline__ float bflo(u32 v){ return __uint_as_float(v<<16); }
__device__ __forceinline__ float bfhi(u32 v){ return __uint_as_float(v & 0xffff0000u); }
__device__ __forceinline__ u16 f2bf(float f){
    u32 u = __float_as_uint(f);
    return (u16)((u + 0x7fffu + ((u>>16)&1u)) >> 16);   // RNE
}
__device__ __forceinline__ u32 pack2(float a, float b){
    return (u32)f2bf(a) | ((u32)f2bf(b) << 16);
}

// ---- CSR build -------------------------------------------------------------
__global__ void k_hist(const int* __restrict__ dst, int* __restrict__ counts){
    int e = blockIdx.x*256 + threadIdx.x;
    if(e < NE) atomicAdd(&counts[dst[e]], 1);
}

__global__ void k_scan(const int* __restrict__ counts, int* __restrict__ rowptr,
                       int* __restrict__ cursor){
    __shared__ int wsum[16];
    int tx = threadIdx.x, lane = tx & 63, wid = tx >> 6;
    int running = 0;
    for(int t = 0; t < (NN + 1023)/1024; ++t){
        int i = t*1024 + tx;
        int v = (i < NN) ? counts[i] : 0;
        int s = v;
        #pragma unroll
        for(int d = 1; d < 64; d <<= 1){ int o = __shfl_up(s, d); if(lane >= d) s += o; }
        if(lane == 63) wsum[wid] = s;
        __syncthreads();
        int woff = 0, total = 0;
        for(int w_ = 0; w_ < 16; ++w_){ int sw = wsum[w_]; total += sw; if(w_ < wid) woff += sw; }
        int ex = running + woff + s - v;   // exclusive prefix
        if(i < NN){ rowptr[i] = ex; cursor[i] = ex; }
        running += total;
        __syncthreads();
    }
    if(tx == 0) rowptr[NN] = running;
}

__global__ void k_scatter(const int* __restrict__ src, const int* __restrict__ dst,
                          int* __restrict__ cursor, int* __restrict__ srcs){
    int e = blockIdx.x*256 + threadIdx.x;
    if(e >= NE) return;
    int d = dst[e];
    int p = atomicAdd(&cursor[d], 1);
    srcs[p] = src[e];
}

// ---- input / weight prep for MFMA ------------------------------------------
__global__ void k_prep_h(const float* __restrict__ h, u16* __restrict__ hb){
    int i = blockIdx.x*256 + threadIdx.x;     // over NN*KP0
    if(i >= NN*KP0) return;
    int n = i / KP0, k = i - n*KP0;
    hb[i] = (k < KIN) ? f2bf(h[n*KIN + k]) : (u16)0;
}

// W0[h][k][c] f32 -> wt0[h][c][KP0] bf16 (transposed, zero-padded)
__global__ void k_prep_w0(const float* __restrict__ W0, u16* __restrict__ wt){
    int i = blockIdx.x*256 + threadIdx.x;     // over NH*HD*KP0
    if(i >= NH*HD*KP0) return;
    int k = i % KP0; int c = (i/KP0) % HD; int h = i/(KP0*HD);
    wt[i] = (k < KIN) ? f2bf(W0[(h*KIN + k)*HD + c]) : (u16)0;
}

// Wr[h][k][c] f32 -> wt1[h][c][HD] bf16 (transposed)
__global__ void k_prep_w1(const float* __restrict__ Wr, u16* __restrict__ wt){
    int i = blockIdx.x*256 + threadIdx.x;     // over NH*HD*HD
    if(i >= NH*HD*HD) return;
    int k = i % HD; int c = (i/HD) % HD; int h = i/(HD*HD);
    wt[i] = f2bf(Wr[(h*HD + k)*HD + c]);
}

// ---- z = x @ W per head via MFMA (bf16 in, fp32 acc, bf16 out) -------------
// grid (NN/32, NH), 256 threads = 4 waves.
// wave w: nodes n0+(w>>1)*16 .. +16, channels (w&1)*64 .. +64 (4 16x16 tiles).
// A frag: lane l -> x[n0+(l&15)][(l>>4)*8 + j]; B frag from wt[c][k] layout:
// lane l -> wt[c0+(l&15)][(l>>4)*8 + j]. C/D: col=lane&15, row=(lane>>4)*4+reg.
template<int KP>
__global__ void k_gemm_mfma(const u16* __restrict__ xb, const u16* __restrict__ wt,
                            u16* __restrict__ z){
    int h = blockIdx.y;
    int tx = threadIdx.x, lane = tx & 63, w = tx >> 6;
    int n0 = blockIdx.x*32 + (w >> 1)*16;
    int c0 = (w & 1)*64;
    int r16 = lane & 15, kg = lane >> 4;
    const u16* ap = xb + (size_t)(n0 + r16)*KP + kg*8;
    const u16* bp = wt + ((size_t)h*HD + c0 + r16)*KP + kg*8;
    f32x4 acc0 = {0.f,0.f,0.f,0.f}, acc1 = {0.f,0.f,0.f,0.f};
    f32x4 acc2 = {0.f,0.f,0.f,0.f}, acc3 = {0.f,0.f,0.f,0.f};
    #pragma unroll
    for(int k0 = 0; k0 < KP; k0 += 32){
        bf16x8 av = *(const bf16x8*)(ap + k0);
        bf16x8 b0 = *(const bf16x8*)(bp + k0);
        bf16x8 b1 = *(const bf16x8*)(bp + 16*KP + k0);
        bf16x8 b2 = *(const bf16x8*)(bp + 32*KP + k0);
        bf16x8 b3 = *(const bf16x8*)(bp + 48*KP + k0);
        acc0 = __builtin_amdgcn_mfma_f32_16x16x32_bf16(av, b0, acc0, 0, 0, 0);
        acc1 = __builtin_amdgcn_mfma_f32_16x16x32_bf16(av, b1, acc1, 0, 0, 0);
        acc2 = __builtin_amdgcn_mfma_f32_16x16x32_bf16(av, b2, acc2, 0, 0, 0);
        acc3 = __builtin_amdgcn_mfma_f32_16x16x32_bf16(av, b3, acc3, 0, 0, 0);
    }
    int nbase = n0 + kg*4;
    u16* zp = z + ((size_t)nbase*NH + h)*HD + c0 + r16;
    #pragma unroll
    for(int reg = 0; reg < 4; ++reg){
        u16* q = zp + (size_t)reg*NH*HD;
        q[0]  = f2bf(acc0[reg]);
        q[16] = f2bf(acc1[reg]);
        q[32] = f2bf(acc2[reg]);
        q[48] = f2bf(acc3[reg]);
    }
}

// ---- per-node attention dot products es = z.a_src, ed = z.a_dst ------------
__global__ void k_dots(const u16* __restrict__ z, const float* __restrict__ attj,
                       float* __restrict__ es, float* __restrict__ ed){
    int tx = threadIdx.x, lane = tx & 63, w = tx >> 6;
    int n = blockIdx.x*4 + w;
    if(n >= NN) return;
    int ch = lane*2;
    for(int h = 0; h < NH; ++h){
        u32 zz = *(const u32*)(z + (size_t)(n*NH + h)*HD + ch);
        float z0 = bflo(zz);
        float z1 = bfhi(zz);
        const float* a = attj + h*2*HD;
        float ps = z0*a[ch]    + z1*a[ch+1];
        float pd = z0*a[HD+ch] + z1*a[HD+ch+1];
        #pragma unroll
        for(int d = 32; d > 0; d >>= 1){ ps += __shfl_xor(ps, d); pd += __shfl_xor(pd, d); }
        if(lane == 0){ es[n*NH + h] = ps; ed[n*NH + h] = pd; }
    }
}

// ---- fused edge-logit + segment softmax + weighted aggregation + relu ------
__global__ void k_aggregate(const int* __restrict__ rowptr, const int* __restrict__ srcs,
                            const float* __restrict__ es, const float* __restrict__ ed,
                            const u16* __restrict__ z, u16* __restrict__ r){
    int n = blockIdx.x;
    int tx = threadIdx.x, lane = tx & 63, h = tx >> 6;
    int p0 = rowptr[n], p1 = rowptr[n+1];
    int eslot = lane >> 4;       // 0..3
    int cidx  = lane & 15;       // 8 channels each
    float edn = ed[n*NH + h];
    float ssum = 0.f;
    float acc[8];
    #pragma unroll
    for(int k = 0; k < 8; ++k) acc[k] = 0.f;

    for(int base = p0; base < p1; base += 64){
        int p = base + lane;
        int sn = 0; float ex = 0.f;
        if(p < p1){
            sn = srcs[p];
            float e = es[sn*NH + h] + edn;
            e = e >= 0.f ? e : 0.01f*e;          // leaky_relu, slope 0.01
            ex = __expf(e);
        }
        ssum += ex;
        int cnt = min(64, p1 - base);
        int niter = (cnt + 7) >> 3;              // 8 edges per iteration
        for(int i = 0; i < niter; ++i){
            int e0 = i*8 + eslot;                // <= 63
            int e1 = e0 + 4;                     // <= 63 (ex==0 past cnt)
            float a0 = __shfl(ex, e0);
            int   s0 = __shfl(sn, e0);
            float a1 = __shfl(ex, e1);
            int   s1 = __shfl(sn, e1);
            const uint4* q0 = (const uint4*)(z + (s0*NH + h)*HD + cidx*8);
            const uint4* q1 = (const uint4*)(z + (s1*NH + h)*HD + cidx*8);
            uint4 v0 = *q0;
            uint4 v1 = *q1;
            acc[0] += a0*bflo(v0.x); acc[1] += a0*bfhi(v0.x);
            acc[2] += a0*bflo(v0.y); acc[3] += a0*bfhi(v0.y);
            acc[4] += a0*bflo(v0.z); acc[5] += a0*bfhi(v0.z);
            acc[6] += a0*bflo(v0.w); acc[7] += a0*bfhi(v0.w);
            acc[0] += a1*bflo(v1.x); acc[1] += a1*bfhi(v1.x);
            acc[2] += a1*bflo(v1.y); acc[3] += a1*bfhi(v1.y);
            acc[4] += a1*bflo(v1.z); acc[5] += a1*bfhi(v1.z);
            acc[6] += a1*bflo(v1.w); acc[7] += a1*bfhi(v1.w);
        }
    }
    #pragma unroll
    for(int k = 0; k < 8; ++k){
        acc[k] += __shfl_xor(acc[k], 16);
        acc[k] += __shfl_xor(acc[k], 32);
    }
    #pragma unroll
    for(int d = 32; d > 0; d >>= 1) ssum += __shfl_xor(ssum, d);
    float inv = (ssum > 0.f) ? 1.f/ssum : 0.f;
    if(eslot == 0){
        float c0 = fmaxf(acc[0]*inv, 0.f), c1 = fmaxf(acc[1]*inv, 0.f);
        float c2 = fmaxf(acc[2]*inv, 0.f), c3 = fmaxf(acc[3]*inv, 0.f);
        float c4 = fmaxf(acc[4]*inv, 0.f), c5 = fmaxf(acc[5]*inv, 0.f);
        float c6 = fmaxf(acc[6]*inv, 0.f), c7 = fmaxf(acc[7]*inv, 0.f);
        uint4 o;
        o.x = pack2(c0, c1); o.y = pack2(c2, c3);
        o.z = pack2(c4, c5); o.w = pack2(c6, c7);
        *(uint4*)(r + (n*NH + h)*HD + cidx*8) = o;
    }
}

// ---- BatchNorm stats (sum, sumsq per channel) ------------------------------
__global__ void k_bnreduce(const u16* __restrict__ r, float* __restrict__ bnsum,
                           float* __restrict__ bnsqs){
    int c = blockIdx.x*256 + threadIdx.x;   // 0..511
    int nbeg = blockIdx.y * 160;            // 125 chunks * 160 = 20000
    float s = 0.f, s2 = 0.f;
    for(int i = 0; i < 160; ++i){
        float v = bf2f(r[(size_t)(nbeg+i)*512 + c]);
        s += v; s2 += v*v;
    }
    atomicAdd(&bnsum[c], s);
    atomicAdd(&bnsqs[c], s2);
}

__global__ void k_bnfin(const float* __restrict__ bnsum, const float* __restrict__ bnsqs,
                        const float* __restrict__ gamma, const float* __restrict__ beta,
                        float* __restrict__ inv, float* __restrict__ shift){
    int c = blockIdx.x*256 + threadIdx.x;
    if(c >= 512) return;
    float mean = bnsum[c] * (1.f/NN);
    float var  = bnsqs[c] * (1.f/NN) - mean*mean;
    float iv = gamma[c] * rsqrtf(var + BN_EPS);
    inv[c] = iv;
    shift[c] = beta[c] - mean*iv;
}

// ---- BN apply + head softmax mix -> x[N][128] ------------------------------
__global__ void k_headmix(const u16* __restrict__ r, const float* __restrict__ inv,
                          const float* __restrict__ shift, const float* __restrict__ ow,
                          u16* __restrict__ x){
    int tx = threadIdx.x, lane = tx & 63, w = tx >> 6;
    int n = blockIdx.x*4 + w;
    if(n >= NN) return;
    int ch = lane*2;
    float rn[NH][2];
    float sc[NH];
    #pragma unroll
    for(int h = 0; h < NH; ++h){
        int c = h*HD + ch;
        u32 zz = *(const u32*)(r + (size_t)n*512 + c);
        float v0 = bflo(zz)*inv[c]   + shift[c];
        float v1 = bfhi(zz)*inv[c+1] + shift[c+1];
        rn[h][0] = v0; rn[h][1] = v1;
        float p = v0*ow[ch] + v1*ow[ch+1];
        #pragma unroll
        for(int d = 32; d > 0; d >>= 1) p += __shfl_xor(p, d);
        sc[h] = p;
    }
    float m = fmaxf(fmaxf(sc[0], sc[1]), fmaxf(sc[2], sc[3]));
    float e0 = __expf(sc[0]-m), e1 = __expf(sc[1]-m), e2 = __expf(sc[2]-m), e3 = __expf(sc[3]-m);
    float is = 1.f/(e0+e1+e2+e3);
    float x0 = (e0*rn[0][0] + e1*rn[1][0] + e2*rn[2][0] + e3*rn[3][0])*is;
    float x1 = (e0*rn[0][1] + e1*rn[1][1] + e2*rn[2][1] + e3*rn[3][1])*is;
    *(u32*)(x + (size_t)n*HD + ch) = pack2(x0, x1);
}

// ---- per-graph mean (graph_ids sorted -> contiguous ranges, no atomics) ----
__global__ void k_gmean(const int* __restrict__ gid, const u16* __restrict__ x,
                        float* __restrict__ out){
    int g = blockIdx.x;
    int tx = threadIdx.x, lane = tx & 63, w = tx >> 6;
    int lo = 0, hi = NN;
    while(lo < hi){ int mid = (lo + hi) >> 1; if(gid[mid] < g) lo = mid + 1; else hi = mid; }
    int start = lo;
    hi = NN;
    while(lo < hi){ int mid = (lo + hi) >> 1; if(gid[mid] < g + 1) lo = mid + 1; else hi = mid; }
    int end = lo;
    float a0 = 0.f, a1 = 0.f;
    for(int n = start + w; n < end; n += 4){
        u32 zz = *(const u32*)(x + (size_t)n*HD + lane*2);
        a0 += bflo(zz);
        a1 += bfhi(zz);
    }
    __shared__ float sm[4][HD];
    sm[w][lane*2]     = a0;
    sm[w][lane*2 + 1] = a1;
    __syncthreads();
    if(tx < HD){
        float s = sm[0][tx] + sm[1][tx] + sm[2][tx] + sm[3][tx];
        float cnt = (float)(end - start);
        out[g*HD + tx] = s / fmaxf(cnt, 1.f);
    }
}

extern "C" void kernel_launch(void* const* d_in, const int* in_sizes, int n_in,
                              void* d_out, int out_size, void* d_ws, size_t ws_size,
                              hipStream_t stream){
    const float* h     = (const float*)d_in[0];
    const int*   src   = (const int*)  d_in[1];
    const int*   dst   = (const int*)  d_in[2];
    const int*   gid   = (const int*)  d_in[3];
    const float* W0    = (const float*)d_in[4];
    const float* Wr    = (const float*)d_in[5];
    const float* att   = (const float*)d_in[6];
    const float* gamma = (const float*)d_in[7];
    const float* beta  = (const float*)d_in[8];
    const float* ow    = (const float*)d_in[9];

    char* p = (char*)d_ws;
    auto alloc = [&](size_t bytes) -> void* {
        void* q = (void*)p;
        p += (bytes + 255) & ~(size_t)255;
        return q;
    };
    u16*   z      = (u16*)  alloc((size_t)NN*NH*HD*2);   // 20.5 MB
    u16*   r      = (u16*)  alloc((size_t)NN*NH*HD*2);   // 20.5 MB
    u16*   x      = (u16*)  alloc((size_t)NN*HD*2);      // 5.1 MB
    u16*   hb     = (u16*)  alloc((size_t)NN*KP0*2);     // 3.8 MB
    u16*   wt0    = (u16*)  alloc((size_t)NH*HD*KP0*2);
    u16*   wt1    = (u16*)  alloc((size_t)NH*HD*HD*2);
    float* es     = (float*)alloc((size_t)NN*NH*4);
    float* ed     = (float*)alloc((size_t)NN*NH*4);
    int*   counts = (int*)  alloc((size_t)NN*4);
    int*   rowptr = (int*)  alloc((size_t)(NN+1)*4);
    int*   cursor = (int*)  alloc((size_t)NN*4);
    int*   srcs   = (int*)  alloc((size_t)NE*4);
    float* bnsum  = (float*)alloc(1024*4);               // sums[512] + sqs[512]
    float* bnsqs  = bnsum + 512;
    float* bninv  = (float*)alloc(1024*4);               // inv[512] + shift[512]
    float* bnshift= bninv + 512;

    // input/weight prep (bf16 + transpose + pad)
    k_prep_h <<<(NN*KP0+255)/256, 256, 0, stream>>>(h, hb);
    k_prep_w0<<<(NH*HD*KP0+255)/256, 256, 0, stream>>>(W0, wt0);
    k_prep_w1<<<(NH*HD*HD+255)/256, 256, 0, stream>>>(Wr, wt1);

    // CSR build (graph is identical both layers)
    hipMemsetAsync(counts, 0, (size_t)NN*4, stream);
    k_hist   <<<(NE+255)/256, 256, 0, stream>>>(dst, counts);
    k_scan   <<<1, 1024, 0, stream>>>(counts, rowptr, cursor);
    k_scatter<<<(NE+255)/256, 256, 0, stream>>>(src, dst, cursor, srcs);

    for(int j = 0; j < 2; ++j){
        if(j == 0) k_gemm_mfma<KP0><<<dim3(NN/32, NH), 256, 0, stream>>>(hb, wt0, z);
        else       k_gemm_mfma<HD> <<<dim3(NN/32, NH), 256, 0, stream>>>(x,  wt1, z);

        k_dots     <<<NN/4, 256, 0, stream>>>(z, att + j*NH*2*HD, es, ed);
        k_aggregate<<<NN, 256, 0, stream>>>(rowptr, srcs, es, ed, z, r);

        hipMemsetAsync(bnsum, 0, 1024*4, stream);
        k_bnreduce <<<dim3(2,125), 256, 0, stream>>>(r, bnsum, bnsqs);
        k_bnfin    <<<2, 256, 0, stream>>>(bnsum, bnsqs, gamma + j*512, beta + j*512,
                                           bninv, bnshift);
        k_headmix  <<<NN/4, 256, 0, stream>>>(r, bninv, bnshift, ow + j*HD, x);
    }

    k_gmean<<<NG, 256, 0, stream>>>(gid, x, (float*)d_out);
}